// Round 6
// baseline (313.558 us; speedup 1.0000x reference)
//
#include <hip/hip_runtime.h>
#include <stdint.h>

typedef unsigned short u16;
typedef __bf16 bf16x8 __attribute__((ext_vector_type(8)));
typedef unsigned short u16x8 __attribute__((ext_vector_type(8)));
typedef u16x8 u16x8_ma __attribute__((may_alias));
typedef unsigned short u16x4 __attribute__((ext_vector_type(4)));
typedef float f32x4 __attribute__((ext_vector_type(4)));

#define DIN   1024
#define DOUT  4096
#define BM    128
#define BN    128
#define BK    32
#define NTILE 32          // DIN / BK
#define BUFSZ 8192        // u16 per buffer: A[128][32] + B[128][32]

__device__ __forceinline__ u16 f2bf(float f) {
  unsigned u = __float_as_uint(f);
  u += 0x7fffu + ((u >> 16) & 1u);   // round-to-nearest-even (finite inputs)
  return (u16)(u >> 16);
}
__device__ __forceinline__ bf16x8 ldfrag(const u16* p) {
  union { u16x8 u; bf16x8 b; } cv;
  cv.u = *(const u16x8_ma*)p;
  return cv.b;
}
__device__ __forceinline__ f32x4 mfma16(bf16x8 a, bf16x8 b, f32x4 c) {
  return __builtin_amdgcn_mfma_f32_16x16x32_bf16(a, b, c, 0, 0, 0);
}
__device__ __forceinline__ void gload_lds16(const u16* g, u16* l) {
  __builtin_amdgcn_global_load_lds(
      (const __attribute__((address_space(1))) void*)g,
      (__attribute__((address_space(3))) void*)l, 16, 0, 0);
}
__device__ __forceinline__ void wave_lds_fence() {
  __asm__ __volatile__("s_waitcnt lgkmcnt(0)" ::: "memory");
}

// Single prep dispatch: fp32->bf16 bulk converts (X, Wb) + blueprint weight
// convert/transpose, dispatched on blockIdx ranges (all branches block-uniform).
__global__ void prep_all(const float* __restrict__ X, const float* __restrict__ Wb,
                         const float* __restrict__ W1, const float* __restrict__ W2,
                         u16* __restrict__ Xb, u16* __restrict__ Wbb,
                         u16* __restrict__ W1T, u16* __restrict__ W2T) {
  __shared__ u16 tile[8192];
  const int b = blockIdx.x;
  const int t = threadIdx.x;

  if (b < 3072) {
    const float* src; u16* dst; int n4, i, stride;
    if (b < 2048) { src = X;  dst = Xb;  n4 = (8192 * 1024) / 4; i = b * 256 + t;          stride = 2048 * 256; }
    else          { src = Wb; dst = Wbb; n4 = (4096 * 1024) / 4; i = (b - 2048) * 256 + t; stride = 1024 * 256; }
    for (; i < n4; i += stride) {
      f32x4 v = ((const f32x4*)src)[i];
      u16x4 o;
      o.x = f2bf(v.x); o.y = f2bf(v.y); o.z = f2bf(v.z); o.w = f2bf(v.w);
      ((u16x4*)dst)[i] = o;
    }
    return;
  }

  const int s = b - 3072;
  const float* w1 = W1 + s * 8192;
  u16* w1t = W1T + s * 8192;
  for (int i = t; i < 8192; i += 256) tile[i] = f2bf(w1[i]);
  __syncthreads();
  for (int i = t; i < 8192; i += 256) {
    int h = i >> 6, c = i & 63;
    w1t[i] = tile[c * 128 + h];
  }
  __syncthreads();

  const float* w2 = W2 + s * 8192;
  u16* w2t = W2T + s * 8192;
  for (int i = t; i < 8192; i += 256) tile[i] = f2bf(w2[i]);
  __syncthreads();
  for (int i = t; i < 8192; i += 256) {
    int c = i >> 7, h = i & 127;
    w2t[i] = tile[h * 64 + c];
  }
}

// 128x128-tile GEMM, 256 threads (4 waves, 64x64 per wave), BK=32, 3-buffer
// rotation, 48 KB LDS -> TWO co-resident blocks per CU. The two blocks'
// barriers are independent: one block's LDS-read/stage phase overlaps the
// other's MFMA burst (the m97/m114 implicit wave-level overlap — this is the
// TLP that the 1-block/CU 256^2 designs lacked).
// Per K-tile: [8 ds_read -> 4 gload_lds(tile j+2) -> vmcnt(4) -> 16 MFMA ->
// s_barrier]  — ONE barrier + one counted vmcnt per tile.
// Ledger: prologue stages t0,t1 (8 loads), VM4 retires t0. Iter j: stage(j+2)
// brings outstanding to 8; VM4 retires t(j+1) before the barrier publishes
// it. reads(j) drain before the wave's MFMAs (compiler lgkm) which precede
// the barrier, which precedes the j+1-iter overwrite of buf[(j+3)%3=j%3].
// Buffers {j, j+1, j+2} are distinct mod 3 -> race-free.
// Swizzle identical to R4 (2-way = free): stage source chunk (l&3)^((l>>3)&3),
// read chunk quad^((lane15>>1)&3).
// XCD-bijective block swizzle: nwg=2048 (%8==0), s=(id&7)*256+(id>>3).
// Inactive seeds: out == y exactly -> wave-uniform early-out.
__global__ __launch_bounds__(256, 2) void kasmina_fused(
    const u16* __restrict__ X,   const u16* __restrict__ Wb,   // bf16 (pre-converted)
    const float* __restrict__ bb,  const float* __restrict__ b1,
    const float* __restrict__ b2,  const float* __restrict__ alpha,
    const int* __restrict__ active,
    const u16* __restrict__ W1T, const u16* __restrict__ W2T,  // bf16
    float* __restrict__ out)
{
  // u16 units: 3 buffers of 8192 (A[128][32] @ +0, B[128][32] @ +4096).
  // Epilogue reuses [0, 18432) as 4 wave-private Yw/Hw regions of 4608.
  __shared__ u16 lds[24576];

  const int t = threadIdx.x;
  const int w = t >> 6, l = t & 63;
  const int wm = w >> 1, wn = w & 1;           // 2M x 2N waves
  const int lane15 = l & 15, quad = l >> 4;

  // XCD-aware bijective swizzle of the 2048-block grid (x=bn fastest).
  const int wgid = blockIdx.y * 32 + blockIdx.x;
  const int s = (wgid & 7) * 256 + (wgid >> 3);
  const int bn0 = (s & 31) * BN;
  const int bm0 = (s >> 5) * BM;

  f32x4 acc[4][4];
#pragma unroll
  for (int mt = 0; mt < 4; ++mt)
#pragma unroll
    for (int nt = 0; nt < 4; ++nt)
      acc[mt][nt] = (f32x4){0.f, 0.f, 0.f, 0.f};

  // ---- staging lane map: wave w covers rows w*32..+31 of A and of B ----
  const int rl = l >> 2;                              // row within 16
  const int cs = ((l & 3) ^ ((l >> 3) & 3)) << 3;     // swizzled source chunk
  const u16* Ag = X  + (size_t)(bm0 + w * 32 + rl) * DIN + cs;
  const u16* Bg = Wb + (size_t)(bn0 + w * 32 + rl) * DIN + cs;

  // ---- fragment-read map ----
  const int swz = (quad ^ ((lane15 >> 1) & 3)) << 3;
  const int aoff = (wm * 64 + lane15) * 32 + swz;            // + mt*512
  const int boff = 4096 + (wn * 64 + lane15) * 32 + swz;     // + nt*512

#define VM4 __asm__ __volatile__("s_waitcnt vmcnt(4)" ::: "memory")
#define VM0 __asm__ __volatile__("s_waitcnt vmcnt(0)" ::: "memory")

#define STAGE(J) do {                                                    \
    const int kk_ = (J) * BK;                                            \
    u16* dst_ = &lds[((J) % 3) * BUFSZ];                                 \
    gload_lds16(Ag + kk_,            dst_ +        w * 1024);            \
    gload_lds16(Ag + 16 * DIN + kk_, dst_ +  512 + w * 1024);            \
    gload_lds16(Bg + kk_,            dst_ + 4096 + w * 1024);            \
    gload_lds16(Bg + 16 * DIN + kk_, dst_ + 4608 + w * 1024);            \
  } while (0)

  // ---- prologue: stage tiles 0,1 ----
  STAGE(0); STAGE(1);
  VM4;                                 // tile 0 landed (t1's 4 stay in flight)
  __builtin_amdgcn_s_barrier();

  // ---- main loop: 32 K-tiles, one barrier + one counted vmcnt each ----
#pragma unroll 1
  for (int j = 0; j < NTILE; ++j) {
    const u16* bufp = &lds[(j % 3) * BUFSZ];
    bf16x8 afr[4], bfr[4];
#pragma unroll
    for (int nt = 0; nt < 4; ++nt) bfr[nt] = ldfrag(bufp + boff + nt * 512);
#pragma unroll
    for (int mt = 0; mt < 4; ++mt) afr[mt] = ldfrag(bufp + aoff + mt * 512);
    if (j < NTILE - 2) {
      STAGE(j + 2);
      VM4;                             // tile j+1 landed; j+2's 4 in flight
    } else if (j == NTILE - 2) {
      VM0;                             // drain tile 31
    }
    __builtin_amdgcn_s_setprio(1);
#pragma unroll
    for (int mt = 0; mt < 4; ++mt)
#pragma unroll
      for (int nt = 0; nt < 4; ++nt)
        acc[mt][nt] = mfma16(afr[mt], bfr[nt], acc[mt][nt]);
    __builtin_amdgcn_s_setprio(0);
    __builtin_amdgcn_s_barrier();      // publishes tile j+1; WAR fence for j%3
  }
  // final barrier of j=31 doubles as the epilogue LDS-reuse fence.

  // ---------------- epilogue: per-seed MLP + blend ----------------
  const int sidx = (s & 31) * 2 + wn;                // wave's seed
  const int act = active[sidx];                      // wave-uniform
  float bbv[4];
#pragma unroll
  for (int nt = 0; nt < 4; ++nt) bbv[nt] = bb[sidx * 64 + nt * 16 + lane15];

  const size_t orow0 = (size_t)(bm0 + wm * 64);

  if (!act) {
    // a == 0  ->  out = y = base + bb, exactly. Skip the MLP entirely.
#pragma unroll
    for (int mt = 0; mt < 4; ++mt)
#pragma unroll
      for (int nt = 0; nt < 4; ++nt) {
        f32x4 yv = acc[mt][nt];
        const int col = sidx * 64 + nt * 16 + lane15;
#pragma unroll
        for (int r = 0; r < 4; ++r) {
          const size_t row = orow0 + mt * 16 + quad * 4 + r;
          out[row * DOUT + col] = yv[r] + bbv[nt];
        }
      }
    return;   // no block-wide syncs remain; active waves keep their LDS region
  }

  const float aval = alpha[sidx];

  u16* Yw = &lds[w * 4608];        // [32][72] — wave-private
  u16* Hw = Yw + 2304;             // [32][72] — wave-private

#pragma unroll                      // MUST fully unroll: acc[] indices constant
  for (int mh = 0; mh < 2; ++mh) {  // 32-row halves of the wave's 64 rows
    // y (=base chunk incl. bias) -> LDS bf16, A-operand [m][c] layout.
#pragma unroll
    for (int mt = 0; mt < 2; ++mt)
#pragma unroll
      for (int nt = 0; nt < 4; ++nt) {
        f32x4 v = acc[mh * 2 + mt][nt];
        const int col = nt * 16 + lane15;
#pragma unroll
        for (int r = 0; r < 4; ++r)
          Yw[(mt * 16 + quad * 4 + r) * 72 + col] = f2bf(v[r] + bbv[nt]);
      }
    wave_lds_fence();              // Yw write -> read (wave-local)

    f32x4 bp[2][4];
#pragma unroll
    for (int nt = 0; nt < 4; ++nt) {
      const float b2v = b2[sidx * 64 + nt * 16 + lane15];
      const f32x4 tv = (f32x4){b2v, b2v, b2v, b2v};
      bp[0][nt] = tv; bp[1][nt] = tv;
    }

#pragma unroll 1
    for (int hh = 0; hh < 2; ++hh) {  // H=128 in two halves of 64
      f32x4 hc[2][4];
#pragma unroll
      for (int nt = 0; nt < 4; ++nt) {
        const float b1v = b1[sidx * 128 + hh * 64 + nt * 16 + lane15];
        const f32x4 tv = (f32x4){b1v, b1v, b1v, b1v};
        hc[0][nt] = tv; hc[1][nt] = tv;
      }
      // GEMM1: h = y @ W1_s   (M=32, N=64(half), K=64)
      const u16* w1b = W1T + sidx * 8192 + (hh * 64 + lane15) * 64 + quad * 8;
#pragma unroll
      for (int ks = 0; ks < 2; ++ks) {
        bf16x8 af0 = ldfrag(Yw + lane15 * 72 + ks * 32 + quad * 8);
        bf16x8 af1 = ldfrag(Yw + (16 + lane15) * 72 + ks * 32 + quad * 8);
#pragma unroll
        for (int nt = 0; nt < 4; ++nt) {
          bf16x8 bfr = ldfrag(w1b + nt * 1024 + ks * 32);   // L2-hot
          hc[0][nt] = mfma16(af0, bfr, hc[0][nt]);
          hc[1][nt] = mfma16(af1, bfr, hc[1][nt]);
        }
      }
      // relu -> bf16 -> Hs
#pragma unroll
      for (int mt = 0; mt < 2; ++mt)
#pragma unroll
        for (int nt = 0; nt < 4; ++nt) {
          f32x4 v = hc[mt][nt];
          const int col = nt * 16 + lane15;
#pragma unroll
          for (int r = 0; r < 4; ++r) {
            float hv = v[r] > 0.f ? v[r] : 0.f;
            Hw[(mt * 16 + quad * 4 + r) * 72 + col] = f2bf(hv);
          }
        }
      wave_lds_fence();            // Hw write -> read (wave-local)
      // GEMM2: bp += h @ W2_s[half]   (M=32, N=64, K=64)
      const u16* w2b = W2T + sidx * 8192 + lane15 * 128 + hh * 64 + quad * 8;
#pragma unroll
      for (int ks = 0; ks < 2; ++ks) {
        bf16x8 af0 = ldfrag(Hw + lane15 * 72 + ks * 32 + quad * 8);
        bf16x8 af1 = ldfrag(Hw + (16 + lane15) * 72 + ks * 32 + quad * 8);
#pragma unroll
        for (int nt = 0; nt < 4; ++nt) {
          bf16x8 bfr = ldfrag(w2b + nt * 2048 + ks * 32);
          bp[0][nt] = mfma16(af0, bfr, bp[0][nt]);
          bp[1][nt] = mfma16(af1, bfr, bp[1][nt]);
        }
      }
      wave_lds_fence();            // Hw read -> next-iter write (WAR)
    }
    // blend (y in fp32 from acc, unquantized) + fp32 store
#pragma unroll
    for (int mt = 0; mt < 2; ++mt)
#pragma unroll
      for (int nt = 0; nt < 4; ++nt) {
        f32x4 yv = acc[mh * 2 + mt][nt];
        f32x4 pv = bp[mt][nt];
        const int col = sidx * 64 + nt * 16 + lane15;
#pragma unroll
        for (int r = 0; r < 4; ++r) {
          const float y = yv[r] + bbv[nt];
          const float o = (1.0f - aval) * y + aval * pv[r];
          const size_t row = orow0 + mh * 32 + mt * 16 + quad * 4 + r;
          out[row * DOUT + col] = o;
        }
      }
    wave_lds_fence();              // Yw/Hw reuse for next half (WAR)
  }
}

extern "C" void kernel_launch(void* const* d_in, const int* in_sizes, int n_in,
                              void* d_out, int out_size, void* d_ws, size_t ws_size,
                              hipStream_t stream) {
  const float* X     = (const float*)d_in[0];   // [8192][1024] fp32
  const float* Wb    = (const float*)d_in[1];   // [4096][1024] fp32
  const float* bbp   = (const float*)d_in[2];   // [4096]
  const float* W1    = (const float*)d_in[3];   // [64][64][128]
  const float* b1p   = (const float*)d_in[4];   // [64][128]
  const float* W2    = (const float*)d_in[5];   // [64][128][64]
  const float* b2p   = (const float*)d_in[6];   // [64][64]
  const float* alpha = (const float*)d_in[7];   // [64]
  const int*  active = (const int*)d_in[8];     // [64]
  float* out = (float*)d_out;

  // workspace layout (u16 units): W1T 512K | W2T 512K | Xb 8.39M | Wbb 4.19M
  u16* W1T = (u16*)d_ws;
  u16* W2T = W1T + 524288;
  u16* Xb  = W1T + 1048576;
  u16* Wbb = W1T + 9437184;       // total ~27.3 MB

  prep_all<<<3136, 256, 0, stream>>>(X, Wb, W1, W2, Xb, Wbb, W1T, W2T);
  kasmina_fused<<<dim3(32, 64), 256, 0, stream>>>(
      Xb, Wbb, bbp, b1p, b2p, alpha, active, W1T, W2T, out);
}